// Round 1
// baseline (1061.831 us; speedup 1.0000x reference)
//
#include <hip/hip_runtime.h>
#include <cstddef>

#define NN   32
#define CIN  256
#define COUT 256
#define TT   128
#define VV   25
#define KK   3
#define TV   (TT*VV)        // 3200
#define NTVC (NN*TT*VV)     // 102400 samples per channel for BN
#define BN_EPS 1e-5f

// Kernel 1: fused 1x1-conv (pre) + adjacency contraction.
// Writes y2 into d_out (used as scratch until kernel 3 normalizes in place),
// accumulates per-channel sum / sumsq into stats[0..255] / stats[256..511].
__global__ __launch_bounds__(256, 2)
void conv_adj_kernel(const float* __restrict__ x,
                     const float* __restrict__ A,
                     const float* __restrict__ W,
                     const float* __restrict__ b,
                     float* __restrict__ y2,
                     float* __restrict__ stats)
{
    // stride 28 (mult of 4) keeps float4 rows 16B-aligned; reads are
    // wave-uniform broadcasts so bank conflicts don't apply.
    __shared__ __align__(16) float Xs[CIN * 28];
    __shared__ __align__(16) float As[KK * VV * VV];  // 1875 floats

    const int tid = threadIdx.x;
    const int t   = blockIdx.x;
    const int n   = blockIdx.y;

    for (int i = tid; i < KK * VV * VV; i += 256) As[i] = A[i];

    const float* xp = x + (size_t)n * CIN * TV + t * VV;
    for (int i = tid; i < CIN * VV; i += 256) {
        int ci = i / VV;
        int v  = i - ci * VV;
        Xs[ci * 28 + v] = xp[ci * TV + v];
    }
    __syncthreads();

    const int c = tid;  // output channel handled by this thread (all 3 k's)
    float acc0[VV], acc1[VV], acc2[VV];
    {
        float b0 = b[c], b1 = b[COUT + c], b2 = b[2 * COUT + c];
        #pragma unroll
        for (int v = 0; v < VV; ++v) { acc0[v] = b0; acc1[v] = b1; acc2[v] = b2; }
    }

    const float* w0p = W + (size_t)c * CIN;
    const float* w1p = W + (size_t)(COUT + c) * CIN;
    const float* w2p = W + (size_t)(2 * COUT + c) * CIN;

    for (int ci = 0; ci < CIN; ci += 4) {
        float4 wa4 = *(const float4*)(w0p + ci);
        float4 wb4 = *(const float4*)(w1p + ci);
        float4 wc4 = *(const float4*)(w2p + ci);
        float wa[4] = {wa4.x, wa4.y, wa4.z, wa4.w};
        float wb[4] = {wb4.x, wb4.y, wb4.z, wb4.w};
        float wc[4] = {wc4.x, wc4.y, wc4.z, wc4.w};
        #pragma unroll
        for (int u = 0; u < 4; ++u) {
            float xv[28];
            const float* xrow = &Xs[(ci + u) * 28];
            #pragma unroll
            for (int q = 0; q < 7; ++q)
                *(float4*)&xv[q * 4] = *(const float4*)(xrow + q * 4);
            #pragma unroll
            for (int v = 0; v < VV; ++v) {
                acc0[v] += wa[u] * xv[v];
                acc1[v] += wb[u] * xv[v];
                acc2[v] += wc[u] * xv[v];
            }
        }
    }

    // Adjacency: out[w] = sum_k sum_v A[k,v,w] * acc_k[v]
    float out[VV];
    #pragma unroll
    for (int w = 0; w < VV; ++w) out[w] = 0.f;
    for (int v = 0; v < VV; ++v) {
        float a0 = acc0[v], a1 = acc1[v], a2 = acc2[v];
        const float* r0 = &As[v * VV];
        const float* r1 = &As[(VV + v) * VV];
        const float* r2 = &As[(2 * VV + v) * VV];
        #pragma unroll
        for (int w = 0; w < VV; ++w)
            out[w] += r0[w] * a0 + r1[w] * a1 + r2[w] * a2;
    }

    // BN partial stats for this (n,c,t) row
    float s1 = 0.f, s2 = 0.f;
    #pragma unroll
    for (int w = 0; w < VV; ++w) { float o = out[w]; s1 += o; s2 += o * o; }
    atomicAdd(&stats[c], s1);
    atomicAdd(&stats[COUT + c], s2);

    // Stage through LDS (stride 27, odd -> conflict-free) for coalesced store
    __syncthreads();            // everyone done reading Xs/As
    float* Ys = Xs;             // reuse buffer (27*256 < 28*256)
    #pragma unroll
    for (int w = 0; w < VV; ++w) Ys[c * 27 + w] = out[w];
    __syncthreads();

    float* op = y2 + (size_t)n * COUT * TV + t * VV;
    for (int i = tid; i < COUT * VV; i += 256) {
        int cc = i / VV;
        int w  = i - cc * VV;
        op[cc * TV + w] = Ys[cc * 27 + w];
    }
}

// Kernel 2: fold per-channel sums into scale/shift
__global__ void bn_stats_kernel(const float* __restrict__ stats,
                                const float* __restrict__ gamma,
                                const float* __restrict__ beta,
                                float* __restrict__ ss)
{
    int c = threadIdx.x;
    float mu  = stats[c] * (1.f / NTVC);
    float var = stats[COUT + c] * (1.f / NTVC) - mu * mu;
    float sc  = gamma[c] * rsqrtf(var + BN_EPS);
    ss[c]        = sc;
    ss[COUT + c] = beta[c] - mu * sc;
}

// Kernel 3: in-place normalize + ReLU, float4 (3200 % 4 == 0 so a vector
// never crosses a channel boundary)
__global__ __launch_bounds__(256)
void bn_apply_kernel(float* __restrict__ y, const float* __restrict__ ss)
{
    int i = blockIdx.x * 256 + threadIdx.x;
    int f = i * 4;
    int c = (f / TV) & (COUT - 1);
    float sc = ss[c], sh = ss[COUT + c];
    float4 v = ((float4*)y)[i];
    v.x = fmaxf(v.x * sc + sh, 0.f);
    v.y = fmaxf(v.y * sc + sh, 0.f);
    v.z = fmaxf(v.z * sc + sh, 0.f);
    v.w = fmaxf(v.w * sc + sh, 0.f);
    ((float4*)y)[i] = v;
}

extern "C" void kernel_launch(void* const* d_in, const int* in_sizes, int n_in,
                              void* d_out, int out_size, void* d_ws, size_t ws_size,
                              hipStream_t stream)
{
    const float* x     = (const float*)d_in[0];
    const float* A     = (const float*)d_in[1];
    const float* W     = (const float*)d_in[2];
    const float* b     = (const float*)d_in[3];
    const float* gamma = (const float*)d_in[4];
    const float* beta  = (const float*)d_in[5];
    float* out = (float*)d_out;
    float* ws  = (float*)d_ws;   // [0,512): sum/sumsq  [512,1024): scale/shift

    hipMemsetAsync(ws, 0, 2 * COUT * sizeof(float), stream);

    dim3 g1(TT, NN);
    conv_adj_kernel<<<g1, 256, 0, stream>>>(x, A, W, b, out, ws);
    bn_stats_kernel<<<1, 256, 0, stream>>>(ws, gamma, beta, ws + 2 * COUT);

    int nblk = (NN * COUT * TT * VV) / (4 * 256);  // 25600
    bn_apply_kernel<<<nblk, 256, 0, stream>>>(out, ws + 2 * COUT);
}

// Round 2
// 557.488 us; speedup vs baseline: 1.9047x; 1.9047x over previous
//
#include <hip/hip_runtime.h>
#include <cstddef>

#define NN   32
#define CIN  256
#define COUT 256
#define TT   128
#define VV   25
#define KK   3
#define TV   (TT*VV)        // 3200
#define NTVC (NN*TT*VV)     // 102400
#define BN_EPS 1e-5f

typedef __attribute__((ext_vector_type(8))) short bf16x8;   // 8 bf16 = 4 VGPRs
typedef __attribute__((ext_vector_type(4))) float f32x4;    // MFMA C/D

__device__ __forceinline__ unsigned short f2bf(float f) {
    unsigned int u = __float_as_uint(f);
    u = (u + 0x7fffu + ((u >> 16) & 1u)) >> 16;   // RNE
    return (unsigned short)u;
}
__device__ __forceinline__ float bf2f(unsigned short h) {
    return __uint_as_float(((unsigned int)h) << 16);
}

// ---------------- K0: W fp32 -> bf16 ----------------
__global__ __launch_bounds__(256)
void convert_w_kernel(const float* __restrict__ W, unsigned short* __restrict__ Wb) {
    int i = blockIdx.x * 256 + threadIdx.x;   // grid = 768 blocks, exact
    Wb[i] = f2bf(W[i]);
}

// ---------------- K1: x [n][c][tv] fp32 -> xT [n][tv][c] bf16 ----------------
__global__ __launch_bounds__(256)
void transpose_x_kernel(const float* __restrict__ x, unsigned short* __restrict__ xT) {
    __shared__ float T[64][65];
    const int n   = blockIdx.z;
    const int s0  = blockIdx.x * 64;   // 50 tiles
    const int c0  = blockIdx.y * 64;   // 4 tiles
    const int tid = threadIdx.x;
    const int r    = tid >> 4;         // 0..15
    const int col4 = (tid & 15) * 4;

    const float* xp = x + (size_t)(n * CIN + c0) * TV + s0;
    for (int rr = r; rr < 64; rr += 16) {
        float4 v = *(const float4*)(xp + (size_t)rr * TV + col4);
        T[rr][col4 + 0] = v.x; T[rr][col4 + 1] = v.y;
        T[rr][col4 + 2] = v.z; T[rr][col4 + 3] = v.w;
    }
    __syncthreads();
    unsigned short* op = xT + ((size_t)n * TV + s0) * CIN + c0;
    for (int ss = r; ss < 64; ss += 16) {
        ushort4 o;
        o.x = f2bf(T[col4 + 0][ss]);
        o.y = f2bf(T[col4 + 1][ss]);
        o.z = f2bf(T[col4 + 2][ss]);
        o.w = f2bf(T[col4 + 3][ss]);
        *(ushort4*)(op + (size_t)ss * CIN + col4) = o;
    }
}

// ---------------- K2: MFMA GEMM + adjacency + BN stats ----------------
// block = (n, t-pair). 512 threads = 8 waves. Wave wg owns rows o in
// [96*wg, 96*wg+96) (6 M-tiles) x 4 N-tiles over s in [0,50) (tiles at
// s = 0,16,32,34; 34-tile overlaps 32-tile with bitwise-identical values).
__global__ __launch_bounds__(512, 2)
void gemm_adj_kernel(const unsigned short* __restrict__ xT,
                     const unsigned short* __restrict__ Wb,
                     const float* __restrict__ A,
                     const float* __restrict__ b,
                     float* __restrict__ y2,
                     float* __restrict__ stats)
{
    // LDS union:
    //   [0, 26400)        yL  bf16 [50 s][264]   (one k-block per pass)
    //   [26400, 33900)    As  fp32 [3][25][25]
    //   [0, 55296)        OutL fp32 [512][27]    (after adjacency done)
    __shared__ __align__(16) char smem[55296];
    unsigned short* yL = (unsigned short*)smem;
    float* As   = (float*)(smem + 26400);
    float* OutL = (float*)smem;

    const int tid  = threadIdx.x;
    const int lane = tid & 63;
    const int wg   = tid >> 6;      // wave 0..7
    const int ln15 = lane & 15;
    const int quad = lane >> 4;     // 0..3
    const int tp   = blockIdx.x & 63;
    const int n    = blockIdx.x >> 6;
    const int t0   = tp * 2;

    for (int i = tid; i < KK * VV * VV; i += 512) As[i] = A[i];

    const int soff[4] = {0, 16, 32, 34};

    // ---- GEMM with bias folded into accumulator init ----
    f32x4 acc[6][4];
    {
        const int ob = 96 * wg + 4 * quad;
        #pragma unroll
        for (int mt = 0; mt < 6; ++mt) {
            float4 bv = *(const float4*)(b + ob + 16 * mt);
            #pragma unroll
            for (int nt = 0; nt < 4; ++nt) {
                acc[mt][nt][0] = bv.x; acc[mt][nt][1] = bv.y;
                acc[mt][nt][2] = bv.z; acc[mt][nt][3] = bv.w;
            }
        }
    }
    // A-frag: W[96*wg + 16*mt + ln15][ks*32 + quad*8 + j]
    // B-frag: xT[n][t0*25 + soff[nt] + ln15][ks*32 + quad*8 + j]
    const unsigned short* wp = Wb + (size_t)(96 * wg + ln15) * CIN + quad * 8;
    const unsigned short* xp = xT + ((size_t)n * TV + t0 * VV + ln15) * CIN + quad * 8;

    for (int ks = 0; ks < 8; ++ks) {
        bf16x8 bfr[4];
        #pragma unroll
        for (int nt = 0; nt < 4; ++nt)
            bfr[nt] = *(const bf16x8*)(xp + (size_t)soff[nt] * CIN + ks * 32);
        #pragma unroll
        for (int mt = 0; mt < 6; ++mt) {
            bf16x8 afr = *(const bf16x8*)(wp + (size_t)(mt * 16) * CIN + ks * 32);
            #pragma unroll
            for (int nt = 0; nt < 4; ++nt)
                acc[mt][nt] = __builtin_amdgcn_mfma_f32_16x16x32_bf16(
                                  afr, bfr[nt], acc[mt][nt], 0, 0, 0);
        }
    }

    // ---- adjacency via 3 k-passes through LDS ----
    const int c  = tid & 255;
    const int dt = tid >> 8;
    float out[VV];
    #pragma unroll
    for (int w = 0; w < VV; ++w) out[w] = 0.f;

    for (int k = 0; k < KK; ++k) {
        __syncthreads();   // prev pass reads done (and As loaded, k==0)
        #pragma unroll
        for (int mt = 0; mt < 6; ++mt) {
            int o = 96 * wg + 16 * mt;           // tile base row
            if ((o >> 8) == k) {
                int oc = (o & 255) + 4 * quad;   // row within k-block
                #pragma unroll
                for (int nt = 0; nt < 4; ++nt) {
                    int s = soff[nt] + ln15;
                    ushort4 pk;
                    pk.x = f2bf(acc[mt][nt][0]);
                    pk.y = f2bf(acc[mt][nt][1]);
                    pk.z = f2bf(acc[mt][nt][2]);
                    pk.w = f2bf(acc[mt][nt][3]);
                    *(ushort4*)(yL + s * 264 + oc) = pk;
                }
            }
        }
        __syncthreads();
        const float* Ak = As + k * VV * VV;
        #pragma unroll
        for (int v = 0; v < VV; ++v) {
            float yv = bf2f(yL[(dt * VV + v) * 264 + c]);
            const float* Ar = Ak + v * VV;
            #pragma unroll
            for (int w = 0; w < VV; ++w) out[w] += yv * Ar[w];
        }
    }

    // ---- BN partial stats ----
    float s1 = 0.f, s2 = 0.f;
    #pragma unroll
    for (int w = 0; w < VV; ++w) { s1 += out[w]; s2 += out[w] * out[w]; }
    atomicAdd(&stats[c], s1);
    atomicAdd(&stats[COUT + c], s2);

    // ---- coalesced store via LDS ----
    __syncthreads();
    #pragma unroll
    for (int w = 0; w < VV; ++w) OutL[(c * 2 + dt) * 27 + w] = out[w];
    __syncthreads();

    float* op = y2 + (size_t)n * COUT * TV + (size_t)t0 * VV;
    for (int i = tid; i < COUT * 2 * VV; i += 512) {
        int cc = i / (2 * VV);
        int r  = i - cc * 2 * VV;       // 0..49; global (t0*25 + r)
        op[(size_t)cc * TV + r] = OutL[(cc * 2 + r / VV) * 27 + (r % VV)];
    }
}

// ---------------- K3: stats -> scale/shift ----------------
__global__ void bn_stats_kernel(const float* __restrict__ stats,
                                const float* __restrict__ gamma,
                                const float* __restrict__ beta,
                                float* __restrict__ ss)
{
    int c = threadIdx.x;
    float mu  = stats[c] * (1.f / NTVC);
    float var = stats[COUT + c] * (1.f / NTVC) - mu * mu;
    float sc  = gamma[c] * rsqrtf(var + BN_EPS);
    ss[c]        = sc;
    ss[COUT + c] = beta[c] - mu * sc;
}

// ---------------- K4: normalize + ReLU in place ----------------
__global__ __launch_bounds__(256)
void bn_apply_kernel(float* __restrict__ y, const float* __restrict__ ss)
{
    int i = blockIdx.x * 256 + threadIdx.x;
    int f = i * 4;
    int cch = (f / TV) & (COUT - 1);
    float sc = ss[cch], sh = ss[COUT + cch];
    float4 v = ((float4*)y)[i];
    v.x = fmaxf(v.x * sc + sh, 0.f);
    v.y = fmaxf(v.y * sc + sh, 0.f);
    v.z = fmaxf(v.z * sc + sh, 0.f);
    v.w = fmaxf(v.w * sc + sh, 0.f);
    ((float4*)y)[i] = v;
}

extern "C" void kernel_launch(void* const* d_in, const int* in_sizes, int n_in,
                              void* d_out, int out_size, void* d_ws, size_t ws_size,
                              hipStream_t stream)
{
    const float* x     = (const float*)d_in[0];
    const float* A     = (const float*)d_in[1];
    const float* W     = (const float*)d_in[2];
    const float* b     = (const float*)d_in[3];
    const float* gamma = (const float*)d_in[4];
    const float* beta  = (const float*)d_in[5];
    float* out = (float*)d_out;

    // ws layout (bytes): [0,2048) stats  [2048,4096) scale/shift
    //                    [4096, +393216) W bf16
    //                    [397312, +52428800) xT bf16   (total ~52.8 MB)
    float* stats = (float*)d_ws;
    float* ss    = stats + 512;
    unsigned short* Wb  = (unsigned short*)((char*)d_ws + 4096);
    unsigned short* xTb = (unsigned short*)((char*)d_ws + 4096 + (size_t)KK * COUT * CIN * 2);

    hipMemsetAsync(stats, 0, 2 * COUT * sizeof(float), stream);

    convert_w_kernel<<<(KK * COUT * CIN) / 256, 256, 0, stream>>>(W, Wb);
    transpose_x_kernel<<<dim3(TV / 64, CIN / 64, NN), 256, 0, stream>>>(x, xTb);
    gemm_adj_kernel<<<NN * (TT / 2), 512, 0, stream>>>(xTb, Wb, A, b, out, stats);
    bn_stats_kernel<<<1, 256, 0, stream>>>(stats, gamma, beta, ss);
    bn_apply_kernel<<<(NN * COUT * TT * VV) / (4 * 256), 256, 0, stream>>>(out, ss);
}

// Round 3
// 479.484 us; speedup vs baseline: 2.2145x; 1.1627x over previous
//
#include <hip/hip_runtime.h>
#include <cstddef>

#define NN   32
#define CIN  256
#define COUT 256
#define TT   128
#define VV   25
#define KK   3
#define TV   (TT*VV)        // 3200
#define NTVC (NN*TT*VV)     // 102400
#define BN_EPS 1e-5f

typedef __attribute__((ext_vector_type(8))) short bf16x8;   // 8 bf16 = 4 VGPRs
typedef __attribute__((ext_vector_type(4))) float f32x4;    // MFMA C/D

__device__ __forceinline__ unsigned short f2bf(float f) {
    unsigned int u = __float_as_uint(f);
    u = (u + 0x7fffu + ((u >> 16) & 1u)) >> 16;   // RNE
    return (unsigned short)u;
}

// ---------------- K0: W fp32 -> bf16 ----------------
__global__ __launch_bounds__(256)
void convert_w_kernel(const float* __restrict__ W, unsigned short* __restrict__ Wb) {
    int i = blockIdx.x * 256 + threadIdx.x;   // grid = 768 blocks, exact
    Wb[i] = f2bf(W[i]);
}

// ---------------- K1: x [n][c][tv] fp32 -> xT [n][tv][c] bf16 ----------------
__global__ __launch_bounds__(256)
void transpose_x_kernel(const float* __restrict__ x, unsigned short* __restrict__ xT) {
    __shared__ float T[64][65];
    const int n   = blockIdx.z;
    const int s0  = blockIdx.x * 64;   // 50 tiles
    const int c0  = blockIdx.y * 64;   // 4 tiles
    const int tid = threadIdx.x;
    const int r    = tid >> 4;         // 0..15
    const int col4 = (tid & 15) * 4;

    const float* xp = x + (size_t)(n * CIN + c0) * TV + s0;
    for (int rr = r; rr < 64; rr += 16) {
        float4 v = *(const float4*)(xp + (size_t)rr * TV + col4);
        T[rr][col4 + 0] = v.x; T[rr][col4 + 1] = v.y;
        T[rr][col4 + 2] = v.z; T[rr][col4 + 3] = v.w;
    }
    __syncthreads();
    unsigned short* op = xT + ((size_t)n * TV + s0) * CIN + c0;
    for (int ss = r; ss < 64; ss += 16) {
        ushort4 o;
        o.x = f2bf(T[col4 + 0][ss]);
        o.y = f2bf(T[col4 + 1][ss]);
        o.z = f2bf(T[col4 + 2][ss]);
        o.w = f2bf(T[col4 + 3][ss]);
        *(ushort4*)(op + (size_t)ss * CIN + col4) = o;
    }
}

// ---------------- K2: MFMA conv GEMM + MFMA adjacency ----------------
// block = (n, t-pair), 512 threads = 8 waves.
// Stage A (conv): wave wg owns o in [96wg, 96wg+96) x s-tiles {0,16,32,34}
//   over s in [0,50), s = t'*25 + v.  (round-2-verified)
// Stage B (adjacency): per t'-half, round-trip y through LDS yT[c][kv] bf16
//   (kv = k*32+v, v-pad zeroed, slot swizzle v^(quad*8) on write /
//   (quad*8)^((ln15>>2)*8) on read -> conflict-free b128 reads, 16B aligned),
//   then out[c][w] = sum_kv yT[c][kv] * Ab[w][kv] via 16x16x32 MFMA with
//   Ab zero-padded so w>=25 / v>=25 contribute exact zeros.
__global__ __launch_bounds__(512, 2)
void gemm_adj_kernel(const unsigned short* __restrict__ xT,
                     const unsigned short* __restrict__ Wb,
                     const float* __restrict__ A,
                     const float* __restrict__ b,
                     float* __restrict__ y2)
{
    __shared__ __align__(16) unsigned short yT[CIN * 96];  // 49152 B
    __shared__ __align__(16) unsigned short Ab[32 * 96];   //  6144 B

    const int tid  = threadIdx.x;
    const int lane = tid & 63;
    const int wg   = tid >> 6;      // wave 0..7
    const int ln15 = lane & 15;
    const int quad = lane >> 4;     // 0..3
    const int tp   = blockIdx.x & 63;
    const int n    = blockIdx.x >> 6;
    const int t0   = tp * 2;

    // Ab[w][kv] = A[k][v][w], zero-padded (single pass, no race)
    for (int i = tid; i < 32 * 96; i += 512) {
        int w  = i / 96;
        int kv = i - w * 96;
        int k  = kv >> 5;
        int v  = kv & 31;
        float val = (v < VV && w < VV) ? A[k * VV * VV + v * VV + w] : 0.f;
        Ab[i] = f2bf(val);
    }
    // zero the swizzled v-pad slots of yT (stale LDS could be inf/NaN;
    // Ab pad is 0 but inf*0=NaN, so pad must be finite -> make it 0)
    for (int i = tid; i < CIN * KK * 7; i += 512) {   // 5376
        int c = i / 21;
        int r = i - c * 21;
        int k = r / 7;
        int v = VV + (r - k * 7);
        int slot = v ^ (((c >> 2) & 3) << 3);
        yT[c * 96 + k * 32 + slot] = 0;
    }

    const int soff[4] = {0, 16, 32, 34};

    // ---- Stage A: conv GEMM, bias folded into acc init ----
    f32x4 acc[6][4];
    {
        const int ob = 96 * wg + 4 * quad;
        #pragma unroll
        for (int mt = 0; mt < 6; ++mt) {
            float4 bv = *(const float4*)(b + ob + 16 * mt);
            #pragma unroll
            for (int nt = 0; nt < 4; ++nt) {
                acc[mt][nt][0] = bv.x; acc[mt][nt][1] = bv.y;
                acc[mt][nt][2] = bv.z; acc[mt][nt][3] = bv.w;
            }
        }
    }
    const unsigned short* wp = Wb + (size_t)(96 * wg + ln15) * CIN + quad * 8;
    const unsigned short* xp = xT + ((size_t)n * TV + t0 * VV + ln15) * CIN + quad * 8;

    for (int ks = 0; ks < 8; ++ks) {
        bf16x8 bfr[4];
        #pragma unroll
        for (int nt = 0; nt < 4; ++nt)
            bfr[nt] = *(const bf16x8*)(xp + (size_t)soff[nt] * CIN + ks * 32);
        #pragma unroll
        for (int mt = 0; mt < 6; ++mt) {
            bf16x8 afr = *(const bf16x8*)(wp + (size_t)(mt * 16) * CIN + ks * 32);
            #pragma unroll
            for (int nt = 0; nt < 4; ++nt)
                acc[mt][nt] = __builtin_amdgcn_mfma_f32_16x16x32_bf16(
                                  afr, bfr[nt], acc[mt][nt], 0, 0, 0);
        }
    }

    // ---- Stage B: adjacency via MFMA, one t'-half at a time ----
    bf16x8 bq[3][2];           // Ab B-frags, t'-independent
    const int rswz = (quad * 8) ^ (((ln15 >> 2) & 3) << 3);

    #pragma unroll
    for (int tp1 = 0; tp1 < 2; ++tp1) {
        __syncthreads();       // (tp1=0: init visible; tp1=1: prev reads done)

        // write conv acc -> yT[c][k*32 + (v ^ quad*8)]
        auto wr = [&](int nt, int v, bool pred) {
            if (pred) {
                int slot = v ^ (quad << 3);
                #pragma unroll
                for (int mt = 0; mt < 6; ++mt) {
                    int o  = 96 * wg + 16 * mt;
                    int k  = o >> 8;                   // uniform per tile
                    int cb = (o & 255) + 4 * quad;
                    int base = cb * 96 + k * 32 + slot;
                    #pragma unroll
                    for (int r = 0; r < 4; ++r)
                        yT[base + r * 96] = f2bf(acc[mt][nt][r]);
                }
            }
        };
        if (tp1 == 0) {
            wr(0, ln15, true);                 // s = ln15      -> v = ln15
            wr(1, 16 + ln15, ln15 < 9);        // s = 16+ln15   -> v = 16+ln15
        } else {
            wr(1, ln15 - 9, ln15 >= 9);        // s = 16+ln15   -> v = ln15-9
            wr(2, 7 + ln15, true);             // s = 32+ln15   -> v = 7+ln15
            wr(3, 9 + ln15, true);             // s = 34+ln15   -> v = 9+ln15 (dup ok)
        }
        __syncthreads();

        if (tp1 == 0) {
            #pragma unroll
            for (int k = 0; k < 3; ++k)
                #pragma unroll
                for (int nw = 0; nw < 2; ++nw)
                    bq[k][nw] = *(const bf16x8*)&Ab[(16 * nw + ln15) * 96 + k * 32 + quad * 8];
        }

        #pragma unroll
        for (int it = 0; it < 2; ++it) {
            const int cb = (wg * 2 + it) * 16;
            f32x4 a2[2];
            #pragma unroll
            for (int nw = 0; nw < 2; ++nw)
                #pragma unroll
                for (int r = 0; r < 4; ++r) a2[nw][r] = 0.f;
            #pragma unroll
            for (int k = 0; k < 3; ++k) {
                bf16x8 af = *(const bf16x8*)&yT[(cb + ln15) * 96 + k * 32 + rswz];
                a2[0] = __builtin_amdgcn_mfma_f32_16x16x32_bf16(af, bq[k][0], a2[0], 0, 0, 0);
                a2[1] = __builtin_amdgcn_mfma_f32_16x16x32_bf16(af, bq[k][1], a2[1], 0, 0, 0);
            }
            // store: element (c = cb+4quad+reg, w = 16*nw+ln15), w<25
            const int t = t0 + tp1;
            float* op = y2 + (size_t)n * COUT * TV
                           + (size_t)(cb + 4 * quad) * TV + t * VV;
            #pragma unroll
            for (int r = 0; r < 4; ++r) {
                op[r * TV + ln15] = a2[0][r];
                if (ln15 < 9) op[r * TV + 16 + ln15] = a2[1][r];
            }
        }
    }
}

// ---------------- K3: per-channel sum/sumsq over y2 ----------------
__global__ __launch_bounds__(256)
void bn_reduce_kernel(const float* __restrict__ y, float* __restrict__ stats)
{
    const int c = blockIdx.x;
    const int n = blockIdx.y;
    const float4* p = (const float4*)(y + (size_t)(n * COUT + c) * TV);
    float s1 = 0.f, s2 = 0.f;
    for (int j = threadIdx.x; j < TV / 4; j += 256) {
        float4 v = p[j];
        s1 += v.x + v.y + v.z + v.w;
        s2 += v.x * v.x + v.y * v.y + v.z * v.z + v.w * v.w;
    }
    #pragma unroll
    for (int off = 32; off; off >>= 1) {
        s1 += __shfl_down(s1, off);
        s2 += __shfl_down(s2, off);
    }
    if ((threadIdx.x & 63) == 0) {
        atomicAdd(&stats[c], s1);
        atomicAdd(&stats[COUT + c], s2);
    }
}

// ---------------- K4: stats -> scale/shift ----------------
__global__ void bn_stats_kernel(const float* __restrict__ stats,
                                const float* __restrict__ gamma,
                                const float* __restrict__ beta,
                                float* __restrict__ ss)
{
    int c = threadIdx.x;
    float mu  = stats[c] * (1.f / NTVC);
    float var = stats[COUT + c] * (1.f / NTVC) - mu * mu;
    float sc  = gamma[c] * rsqrtf(var + BN_EPS);
    ss[c]        = sc;
    ss[COUT + c] = beta[c] - mu * sc;
}

// ---------------- K5: normalize + ReLU in place ----------------
__global__ __launch_bounds__(256)
void bn_apply_kernel(float* __restrict__ y, const float* __restrict__ ss)
{
    int i = blockIdx.x * 256 + threadIdx.x;
    int f = i * 4;
    int cch = (f / TV) & (COUT - 1);
    float sc = ss[cch], sh = ss[COUT + cch];
    float4 v = ((float4*)y)[i];
    v.x = fmaxf(v.x * sc + sh, 0.f);
    v.y = fmaxf(v.y * sc + sh, 0.f);
    v.z = fmaxf(v.z * sc + sh, 0.f);
    v.w = fmaxf(v.w * sc + sh, 0.f);
    ((float4*)y)[i] = v;
}

extern "C" void kernel_launch(void* const* d_in, const int* in_sizes, int n_in,
                              void* d_out, int out_size, void* d_ws, size_t ws_size,
                              hipStream_t stream)
{
    const float* x     = (const float*)d_in[0];
    const float* A     = (const float*)d_in[1];
    const float* W     = (const float*)d_in[2];
    const float* b     = (const float*)d_in[3];
    const float* gamma = (const float*)d_in[4];
    const float* beta  = (const float*)d_in[5];
    float* out = (float*)d_out;

    // ws layout (bytes): [0,2048) stats  [2048,4096) scale/shift
    //                    [4096, +393216) W bf16
    //                    [397312, +52428800) xT bf16
    float* stats = (float*)d_ws;
    float* ss    = stats + 512;
    unsigned short* Wb  = (unsigned short*)((char*)d_ws + 4096);
    unsigned short* xTb = (unsigned short*)((char*)d_ws + 4096 + (size_t)KK * COUT * CIN * 2);

    hipMemsetAsync(stats, 0, 2 * COUT * sizeof(float), stream);

    convert_w_kernel<<<(KK * COUT * CIN) / 256, 256, 0, stream>>>(W, Wb);
    transpose_x_kernel<<<dim3(TV / 64, CIN / 64, NN), 256, 0, stream>>>(x, xTb);
    gemm_adj_kernel<<<NN * (TT / 2), 512, 0, stream>>>(xTb, Wb, A, b, out);
    bn_reduce_kernel<<<dim3(COUT, NN), 256, 0, stream>>>(out, stats);
    bn_stats_kernel<<<1, 256, 0, stream>>>(stats, gamma, beta, ss);
    bn_apply_kernel<<<(NN * COUT * TT * VV) / (4 * 256), 256, 0, stream>>>(out, ss);
}